// Round 16
// baseline (289.270 us; speedup 1.0000x reference)
//
#include <hip/hip_runtime.h>
#include <hip/hip_fp16.h>
#include <math.h>

#define NN 100000
#define NE 3200000
#define NB 391            // buckets of 256 nodes
#define NBH 256           // histogram partial blocks
#define CH 4096           // edges per partition chunk
#define NPART ((NE + CH - 1) / CH)   // 782

typedef unsigned long long u64;
typedef _Float16 h2 __attribute__((ext_vector_type(2)));

__device__ inline float2 u2f2(unsigned v) {
    __half2 h = *reinterpret_cast<__half2*>(&v);
    return __half22float2(h);
}

#if __has_builtin(__builtin_amdgcn_fdot2)
__device__ inline float dot2acc(unsigned a, unsigned b, float c) {
    union { unsigned u; h2 h; } ca, cb;
    ca.u = a; cb.u = b;
    return __builtin_amdgcn_fdot2(ca.h, cb.h, c, false);   // v_dot2_f32_f16
}
#else
__device__ inline float dot2acc(unsigned a, unsigned b, float c) {
    float2 fa = u2f2(a), fb = u2f2(b);
    return c + fa.x * fb.x + fa.y * fb.y;
}
#endif

// ---------------- bucket histogram: per-block partials, no global pre-zero ----------------
__global__ __launch_bounds__(256) void bhist_kernel(const int* __restrict__ dst,
                                                    int* __restrict__ part, int e) {
    __shared__ int h[NB];
    int tid = threadIdx.x;
    for (int i = tid; i < NB; i += 256) h[i] = 0;
    __syncthreads();
    for (int i = blockIdx.x * 256 + tid; i < e; i += NBH * 256)
        atomicAdd(&h[dst[i] >> 8], 1);
    __syncthreads();
    for (int i = tid; i < NB; i += 256)
        part[blockIdx.x * NB + i] = h[i];     // overwrite: deterministic, no memset
}

// ---------------- column-sum partials + exclusive scan (unroll 8 for MLP) ----------------
__global__ __launch_bounds__(512) void bscan_kernel(const int* __restrict__ part,
                                                    int* __restrict__ bhist,
                                                    int* __restrict__ boffs,
                                                    int* __restrict__ cursor) {
    __shared__ int s[512];
    int tid = threadIdx.x;
    int v = 0;
    if (tid < NB) {
#pragma unroll 8
        for (int b = 0; b < NBH; ++b) v += part[b * NB + tid];
        bhist[tid] = v;
    }
    s[tid] = (tid < NB) ? v : 0;
    __syncthreads();
    for (int off = 1; off < 512; off <<= 1) {
        int t = (tid >= off) ? s[tid - off] : 0;
        __syncthreads();
        s[tid] += t;
        __syncthreads();
    }
    if (tid < NB) {
        int ex = s[tid] - v;
        boffs[tid] = ex;
        cursor[tid] = ex;
    }
}

// ---------------- partition: lean 5-phase counting-sort, 512 threads ----------------
// NOTE: src/dst loads stay PLAIN (phase 4 re-reads the phase-1 chunk from L2).
__global__ __launch_bounds__(512) void partition_kernel(
        const int* __restrict__ src, const int* __restrict__ dst,
        int* __restrict__ cursor, int* __restrict__ adj, int e) {
    __shared__ int scnt[NB];
    __shared__ int sbase[NB];
    __shared__ int lexcl[NB];
    __shared__ int cur[NB];
    __shared__ int s[512];
    __shared__ int sdata[CH];

    int tid = threadIdx.x;
    int chunk0 = blockIdx.x * CH;

    for (int i = tid; i < NB; i += 512) scnt[i] = 0;
    __syncthreads();

#pragma unroll
    for (int k = 0; k < CH / 512; ++k) {
        int i = chunk0 + k * 512 + tid;
        if (i < e) atomicAdd(&scnt[dst[i] >> 8], 1);
    }
    __syncthreads();

    for (int b = tid; b < NB; b += 512)
        if (scnt[b]) sbase[b] = atomicAdd(&cursor[b], scnt[b]);

    s[tid] = (tid < NB) ? scnt[tid] : 0;
    __syncthreads();
    for (int off = 1; off < 512; off <<= 1) {
        int t = (tid >= off) ? s[tid - off] : 0;
        __syncthreads();
        s[tid] += t;
        __syncthreads();
    }
    if (tid < NB) {
        int ex = s[tid] - scnt[tid];
        lexcl[tid] = ex;
        cur[tid] = ex;
    }
    __syncthreads();

#pragma unroll
    for (int k = 0; k < CH / 512; ++k) {
        int i = chunk0 + k * 512 + tid;
        if (i < e) {
            int sv = src[i], d = dst[i];
            int b = d >> 8;
            int p = atomicAdd(&cur[b], 1);
            sdata[p] = (sv << 8) | (d & 255);
        }
    }
    __syncthreads();

    for (int b = tid; b < NB; b += 512) {
        int cb = scnt[b];
        if (cb) {
            int base = sbase[b];
            int start = lexcl[b];
            for (int k2 = 0; k2 < cb; ++k2)
                adj[base + k2] = sdata[start + k2];
        }
    }
}

// ---------------- per-bucket node-sort -> adj2 + rowptr + dinv (512 threads) ----------------
__global__ __launch_bounds__(512) void csr_kernel(
        const int* __restrict__ bhist, const int* __restrict__ boffs,
        const int* __restrict__ adj, int* __restrict__ adj2,
        int* __restrict__ rowptr, float* __restrict__ dinv, int n) {
    __shared__ int cnt[256];
    __shared__ int s[256];
    __shared__ int cur[256];
    int tid = threadIdx.x;
    int b = blockIdx.x;
    if (tid < 256) cnt[tid] = 0;
    __syncthreads();
    int ebeg = boffs[b], ecnt = bhist[b];
    for (int j = tid; j < ecnt; j += 512)
        atomicAdd(&cnt[adj[ebeg + j] & 255], 1);
    __syncthreads();
    int v = 0;
    if (tid < 256) { v = cnt[tid]; s[tid] = v; }
    __syncthreads();
    for (int off = 1; off < 256; off <<= 1) {
        int t = 0;
        if (tid < 256 && tid >= off) t = s[tid - off];
        __syncthreads();
        if (tid < 256) s[tid] += t;
        __syncthreads();
    }
    if (tid < 256) {
        int excl = s[tid] - v;
        cur[tid] = excl;
        int node = b * 256 + tid;
        if (node < n) {
            rowptr[node] = ebeg + excl;
            dinv[node] = rsqrtf((float)v + 1.0f);
        }
        if (node == n) rowptr[n] = ebeg + excl;   // sentinel == e
    }
    __syncthreads();
    for (int j = tid; j < ecnt; j += 512) {
        int w = adj[ebeg + j];
        int p = atomicAdd(&cur[w & 255], 1);
        adj2[ebeg + p] = w >> 8;
    }
}

// ---------------- layer 1 GEMM: split fp16 tables g1a (cols 0-15), g1b (cols 16-31) ----------------
__global__ __launch_bounds__(256) void gemm1_kernel(
        const float* __restrict__ x, const float* __restrict__ W1,
        const float* __restrict__ dinv, __half* __restrict__ g1a,
        __half* __restrict__ g1b, int n) {
    __shared__ float sW[64 * 32];     // sW[k*32+c] = W1[c*64+k]
    __shared__ float sX[32 * 65];     // padded stride 65
    int tid = threadIdx.x;
    for (int idx = tid; idx < 2048; idx += 256) {
        int k = idx >> 5, c = idx & 31;
        sW[idx] = W1[c * 64 + k];
    }
    int row0 = blockIdx.x * 32;
    for (int idx = tid; idx < 512; idx += 256) {   // 512 float4 = 32 rows x 16
        int r = idx >> 4, q = idx & 15;
        int grow = row0 + r;
        float4 v = (grow < n) ? ((const float4*)x)[(size_t)grow * 16 + q]
                              : make_float4(0.f, 0.f, 0.f, 0.f);
        float* dp = &sX[r * 65 + q * 4];
        dp[0] = v.x; dp[1] = v.y; dp[2] = v.z; dp[3] = v.w;
    }
    __syncthreads();
    int r = tid >> 3, cg = tid & 7;
    const float4* sW4 = (const float4*)sW;
    float4 acc = make_float4(0.f, 0.f, 0.f, 0.f);
#pragma unroll
    for (int k = 0; k < 64; ++k) {
        float xk = sX[r * 65 + k];
        float4 w = sW4[k * 8 + cg];
        acc.x += xk * w.x; acc.y += xk * w.y; acc.z += xk * w.z; acc.w += xk * w.w;
    }
    int grow = row0 + r;
    if (grow < n) {
        float di = dinv[grow];
        __half2 h0 = __float22half2_rn(make_float2(acc.x * di, acc.y * di));
        __half2 h1 = __float22half2_rn(make_float2(acc.z * di, acc.w * di));
        uint2 packed;
        packed.x = *(unsigned*)&h0;
        packed.y = *(unsigned*)&h1;
        if (cg < 4) ((uint2*)g1a)[(size_t)grow * 4 + cg] = packed;
        else        ((uint2*)g1b)[(size_t)grow * 4 + (cg - 4)] = packed;
    }
}

// ---------------- layer 1 aggregation: nt-load adj2 stream, keep table L2-resident ----------------
__global__ __launch_bounds__(256) void agg1_kernel(
        const int* __restrict__ rowptr, const int* __restrict__ adj2,
        const float* __restrict__ dinv, const __half* __restrict__ gh,
        const float* __restrict__ b1, float* __restrict__ agg1, int n, int pass) {
    int t = blockIdx.x * blockDim.x + threadIdx.x;
    int node = t >> 3;
    if (node >= n) return;
    int c2 = t & 7;
    const unsigned* G = (const unsigned*)gh;
    float2 acc = u2f2(G[(size_t)node * 8 + c2]);   // self-loop (pre-scaled by dinv)
    int j = rowptr[node], end = rowptr[node + 1];
    for (; j + 7 < end; j += 8) {                   // 8 independent gathers in flight
        int s0 = __builtin_nontemporal_load(&adj2[j]);
        int s1 = __builtin_nontemporal_load(&adj2[j + 1]);
        int s2 = __builtin_nontemporal_load(&adj2[j + 2]);
        int s3 = __builtin_nontemporal_load(&adj2[j + 3]);
        int s4 = __builtin_nontemporal_load(&adj2[j + 4]);
        int s5 = __builtin_nontemporal_load(&adj2[j + 5]);
        int s6 = __builtin_nontemporal_load(&adj2[j + 6]);
        int s7 = __builtin_nontemporal_load(&adj2[j + 7]);
        float2 v0 = u2f2(G[(size_t)s0 * 8 + c2]);
        float2 v1 = u2f2(G[(size_t)s1 * 8 + c2]);
        float2 v2 = u2f2(G[(size_t)s2 * 8 + c2]);
        float2 v3 = u2f2(G[(size_t)s3 * 8 + c2]);
        float2 v4 = u2f2(G[(size_t)s4 * 8 + c2]);
        float2 v5 = u2f2(G[(size_t)s5 * 8 + c2]);
        float2 v6 = u2f2(G[(size_t)s6 * 8 + c2]);
        float2 v7 = u2f2(G[(size_t)s7 * 8 + c2]);
        acc.x += ((v0.x + v1.x) + (v2.x + v3.x)) + ((v4.x + v5.x) + (v6.x + v7.x));
        acc.y += ((v0.y + v1.y) + (v2.y + v3.y)) + ((v4.y + v5.y) + (v6.y + v7.y));
    }
    for (; j + 3 < end; j += 4) {
        int s0 = __builtin_nontemporal_load(&adj2[j]);
        int s1 = __builtin_nontemporal_load(&adj2[j + 1]);
        int s2 = __builtin_nontemporal_load(&adj2[j + 2]);
        int s3 = __builtin_nontemporal_load(&adj2[j + 3]);
        float2 v0 = u2f2(G[(size_t)s0 * 8 + c2]);
        float2 v1 = u2f2(G[(size_t)s1 * 8 + c2]);
        float2 v2 = u2f2(G[(size_t)s2 * 8 + c2]);
        float2 v3 = u2f2(G[(size_t)s3 * 8 + c2]);
        acc.x += (v0.x + v1.x) + (v2.x + v3.x);
        acc.y += (v0.y + v1.y) + (v2.y + v3.y);
    }
    for (; j < end; ++j) {
        float2 v = u2f2(G[(size_t)__builtin_nontemporal_load(&adj2[j]) * 8 + c2]);
        acc.x += v.x; acc.y += v.y;
    }
    float di = dinv[node];
    float2 bb = ((const float2*)b1)[pass * 8 + c2];
    float2 outv = make_float2(bb.x + di * acc.x, bb.y + di * acc.y);
    ((float2*)agg1)[(size_t)node * 16 + pass * 8 + c2] = outv;
}

// ---------------- layer 2 GEMM: 64-row tile, float4 W reads ----------------
__global__ __launch_bounds__(256) void gemm2_kernel(
        const float* __restrict__ agg1, const float* __restrict__ W2,
        const float* __restrict__ dinv, __half* __restrict__ g2h, int n) {
    __shared__ float sW[32 * 16];     // sW[k*16+c] = W2[c*32+k]
    __shared__ float sH[64 * 33];     // padded
    int tid = threadIdx.x;
    for (int idx = tid; idx < 512; idx += 256) {
        int k = idx >> 4, c = idx & 15;
        sW[idx] = W2[c * 32 + k];
    }
    int row0 = blockIdx.x * 64;
    for (int idx = tid; idx < 512; idx += 256) {   // 512 float4 = 64 rows x 8
        int r = idx >> 3, q = idx & 7;
        int grow = row0 + r;
        float4 v = (grow < n) ? ((const float4*)agg1)[(size_t)grow * 8 + q]
                              : make_float4(0.f, 0.f, 0.f, 0.f);
        float* dp = &sH[r * 33 + q * 4];
        dp[0] = fmaxf(v.x, 0.f); dp[1] = fmaxf(v.y, 0.f);
        dp[2] = fmaxf(v.z, 0.f); dp[3] = fmaxf(v.w, 0.f);
    }
    __syncthreads();
    int r = tid >> 2, cg = tid & 3;
    const float4* sW4 = (const float4*)sW;
    float4 acc = make_float4(0.f, 0.f, 0.f, 0.f);
#pragma unroll
    for (int k = 0; k < 32; ++k) {
        float hk = sH[r * 33 + k];
        float4 w = sW4[k * 4 + cg];
        acc.x += hk * w.x; acc.y += hk * w.y; acc.z += hk * w.z; acc.w += hk * w.w;
    }
    int grow = row0 + r;
    if (grow < n) {
        float di = dinv[grow];
        __half2 h0 = __float22half2_rn(make_float2(acc.x * di, acc.y * di));
        __half2 h1 = __float22half2_rn(make_float2(acc.z * di, acc.w * di));
        uint2 packed;
        packed.x = *(unsigned*)&h0;
        packed.y = *(unsigned*)&h1;
        ((uint2*)g2h)[(size_t)grow * 4 + cg] = packed;
    }
}

// ---------------- layer 2 aggregation: nt-load adj2 stream ----------------
__global__ __launch_bounds__(256) void agg2_kernel(
        const int* __restrict__ rowptr, const int* __restrict__ adj2,
        const float* __restrict__ dinv, const __half* __restrict__ g2h,
        const float* __restrict__ b2, __half* __restrict__ zh, int n) {
    int t = blockIdx.x * blockDim.x + threadIdx.x;
    int node = t >> 3;
    if (node >= n) return;
    int c2 = t & 7;
    const unsigned* G = (const unsigned*)g2h;
    float2 acc = u2f2(G[(size_t)node * 8 + c2]);
    int j = rowptr[node], end = rowptr[node + 1];
    for (; j + 7 < end; j += 8) {
        int s0 = __builtin_nontemporal_load(&adj2[j]);
        int s1 = __builtin_nontemporal_load(&adj2[j + 1]);
        int s2 = __builtin_nontemporal_load(&adj2[j + 2]);
        int s3 = __builtin_nontemporal_load(&adj2[j + 3]);
        int s4 = __builtin_nontemporal_load(&adj2[j + 4]);
        int s5 = __builtin_nontemporal_load(&adj2[j + 5]);
        int s6 = __builtin_nontemporal_load(&adj2[j + 6]);
        int s7 = __builtin_nontemporal_load(&adj2[j + 7]);
        float2 v0 = u2f2(G[(size_t)s0 * 8 + c2]);
        float2 v1 = u2f2(G[(size_t)s1 * 8 + c2]);
        float2 v2 = u2f2(G[(size_t)s2 * 8 + c2]);
        float2 v3 = u2f2(G[(size_t)s3 * 8 + c2]);
        float2 v4 = u2f2(G[(size_t)s4 * 8 + c2]);
        float2 v5 = u2f2(G[(size_t)s5 * 8 + c2]);
        float2 v6 = u2f2(G[(size_t)s6 * 8 + c2]);
        float2 v7 = u2f2(G[(size_t)s7 * 8 + c2]);
        acc.x += ((v0.x + v1.x) + (v2.x + v3.x)) + ((v4.x + v5.x) + (v6.x + v7.x));
        acc.y += ((v0.y + v1.y) + (v2.y + v3.y)) + ((v4.y + v5.y) + (v6.y + v7.y));
    }
    for (; j + 3 < end; j += 4) {
        int s0 = __builtin_nontemporal_load(&adj2[j]);
        int s1 = __builtin_nontemporal_load(&adj2[j + 1]);
        int s2 = __builtin_nontemporal_load(&adj2[j + 2]);
        int s3 = __builtin_nontemporal_load(&adj2[j + 3]);
        float2 v0 = u2f2(G[(size_t)s0 * 8 + c2]);
        float2 v1 = u2f2(G[(size_t)s1 * 8 + c2]);
        float2 v2 = u2f2(G[(size_t)s2 * 8 + c2]);
        float2 v3 = u2f2(G[(size_t)s3 * 8 + c2]);
        acc.x += (v0.x + v1.x) + (v2.x + v3.x);
        acc.y += (v0.y + v1.y) + (v2.y + v3.y);
    }
    for (; j < end; ++j) {
        float2 v = u2f2(G[(size_t)__builtin_nontemporal_load(&adj2[j]) * 8 + c2]);
        acc.x += v.x; acc.y += v.y;
    }
    float di = dinv[node];
    float2 bb = ((const float2*)b2)[c2];
    __half2 outv = __float22half2_rn(make_float2(bb.x + di * acc.x, bb.y + di * acc.y));
    ((__half2*)zh)[(size_t)node * 8 + c2] = outv;
}

// ---------------- decode: pair-lane + fdot2; nt-load index streams (protect z in L2) ----------------
__global__ __launch_bounds__(256) void decode_kernel(
        const int* __restrict__ src, const int* __restrict__ dst,
        const __half* __restrict__ zh, float* __restrict__ out, int e) {
    int t = blockIdx.x * blockDim.x + threadIdx.x;
    int edge = t >> 1;
    if (edge >= e) return;
    int half = t & 1;
    int s = __builtin_nontemporal_load(&src[edge]);
    int d = __builtin_nontemporal_load(&dst[edge]);
    uint4 a = *((const uint4*)(zh + (size_t)s * 16) + half);
    uint4 b = *((const uint4*)(zh + (size_t)d * 16) + half);
    float partial = 0.f;
    partial = dot2acc(a.x, b.x, partial);
    partial = dot2acc(a.y, b.y, partial);
    partial = dot2acc(a.z, b.z, partial);
    partial = dot2acc(a.w, b.w, partial);
    float total = partial + __shfl_xor(partial, 1, 64);
    if (half == 0)
        out[edge] = 1.0f / (1.0f + expf(-total));
}

extern "C" void kernel_launch(void* const* d_in, const int* in_sizes, int n_in,
                              void* d_out, int out_size, void* d_ws, size_t ws_size,
                              hipStream_t stream) {
    const float* x   = (const float*)d_in[0];
    const int* eidx  = (const int*)d_in[1];
    const float* W1  = (const float*)d_in[2];
    const float* b1  = (const float*)d_in[3];
    const float* W2  = (const float*)d_in[4];
    const float* b2  = (const float*)d_in[5];
    float* out = (float*)d_out;

    const int n = NN;
    const int e = NE;
    const int* src = eidx;
    const int* dst = eidx + e;

    // workspace layout (all segments 16B-aligned)
    int* bhist   = (int*)d_ws;                 // 512
    int* boffs   = bhist + 512;                // 512
    int* cursor  = boffs + 512;                // 512
    int* rowptr  = cursor + 512;               // NN+1 (pad 100004)
    int* adj     = rowptr + 100004;            // NE packed (dead after csr)
    int* adj2    = adj + e;                    // NE node-sorted srcs
    float* dinv  = (float*)(adj2 + e);         // NN
    __half* g1a  = (__half*)adj;               // alias: NN*16 halves (3.2MB) - cols 0..15
    __half* g1b  = g1a + (size_t)n * 16;       // NN*16 halves (3.2MB) - cols 16..31
    float* agg1  = dinv + n;                   // NN*32 f32
    __half* g2h  = (__half*)(agg1 + (size_t)n * 32);   // NN*16 halves
    __half* zh   = g2h + (size_t)n * 16;               // NN*16 halves
    int* part    = (int*)(zh + (size_t)n * 16);        // NBH*NB partial histograms

    dim3 blk(256);

    // CSR build (no memset anywhere: part rows are fully overwritten each call)
    bhist_kernel<<<NBH, blk, 0, stream>>>(dst, part, e);
    bscan_kernel<<<1, 512, 0, stream>>>(part, bhist, boffs, cursor);
    partition_kernel<<<NPART, 512, 0, stream>>>(src, dst, cursor, adj, e);
    csr_kernel<<<NB, 512, 0, stream>>>(bhist, boffs, adj, adj2, rowptr, dinv, n);

    // layer 1
    gemm1_kernel<<<(n + 31) / 32, blk, 0, stream>>>(x, W1, dinv, g1a, g1b, n);
    agg1_kernel<<<(n * 8 + 255) / 256, blk, 0, stream>>>(rowptr, adj2, dinv, g1a, b1, agg1, n, 0);
    agg1_kernel<<<(n * 8 + 255) / 256, blk, 0, stream>>>(rowptr, adj2, dinv, g1b, b1, agg1, n, 1);

    // layer 2
    gemm2_kernel<<<(n + 63) / 64, blk, 0, stream>>>(agg1, W2, dinv, g2h, n);
    agg2_kernel<<<(n * 8 + 255) / 256, blk, 0, stream>>>(rowptr, adj2, dinv, g2h, b2, zh, n);

    // decode: 2 threads per edge
    decode_kernel<<<((e * 2) + 255) / 256, blk, 0, stream>>>(src, dst, zh, out, e);
}

// Round 17
// 234.711 us; speedup vs baseline: 1.2325x; 1.2325x over previous
//
#include <hip/hip_runtime.h>
#include <hip/hip_fp16.h>
#include <math.h>

#define NN 100000
#define NE 3200000
#define NB 391            // buckets of 256 nodes
#define NBH 256           // histogram partial blocks
#define CH 4096           // edges per partition chunk
#define NPART ((NE + CH - 1) / CH)   // 782

typedef unsigned long long u64;
typedef _Float16 h2 __attribute__((ext_vector_type(2)));

__device__ inline float2 u2f2(unsigned v) {
    __half2 h = *reinterpret_cast<__half2*>(&v);
    return __half22float2(h);
}

#if __has_builtin(__builtin_amdgcn_fdot2)
__device__ inline float dot2acc(unsigned a, unsigned b, float c) {
    union { unsigned u; h2 h; } ca, cb;
    ca.u = a; cb.u = b;
    return __builtin_amdgcn_fdot2(ca.h, cb.h, c, false);   // v_dot2_f32_f16
}
#else
__device__ inline float dot2acc(unsigned a, unsigned b, float c) {
    float2 fa = u2f2(a), fb = u2f2(b);
    return c + fa.x * fb.x + fa.y * fb.y;
}
#endif

// ---------------- bucket histogram: per-block partials, no global pre-zero ----------------
__global__ __launch_bounds__(256) void bhist_kernel(const int* __restrict__ dst,
                                                    int* __restrict__ part, int e) {
    __shared__ int h[NB];
    int tid = threadIdx.x;
    for (int i = tid; i < NB; i += 256) h[i] = 0;
    __syncthreads();
    for (int i = blockIdx.x * 256 + tid; i < e; i += NBH * 256)
        atomicAdd(&h[dst[i] >> 8], 1);
    __syncthreads();
    for (int i = tid; i < NB; i += 256)
        part[blockIdx.x * NB + i] = h[i];     // overwrite: deterministic, no memset
}

// ---------------- column-sum partials + exclusive scan ----------------
__global__ __launch_bounds__(512) void bscan_kernel(const int* __restrict__ part,
                                                    int* __restrict__ bhist,
                                                    int* __restrict__ boffs,
                                                    int* __restrict__ cursor) {
    __shared__ int s[512];
    int tid = threadIdx.x;
    int v = 0;
    if (tid < NB) {
#pragma unroll 8
        for (int b = 0; b < NBH; ++b) v += part[b * NB + tid];
        bhist[tid] = v;
    }
    s[tid] = (tid < NB) ? v : 0;
    __syncthreads();
    for (int off = 1; off < 512; off <<= 1) {
        int t = (tid >= off) ? s[tid - off] : 0;
        __syncthreads();
        s[tid] += t;
        __syncthreads();
    }
    if (tid < NB) {
        int ex = s[tid] - v;
        boffs[tid] = ex;
        cursor[tid] = ex;
    }
}

// ---------------- partition: lean 5-phase counting-sort, 512 threads ----------------
__global__ __launch_bounds__(512) void partition_kernel(
        const int* __restrict__ src, const int* __restrict__ dst,
        int* __restrict__ cursor, int* __restrict__ adj, int e) {
    __shared__ int scnt[NB];
    __shared__ int sbase[NB];
    __shared__ int lexcl[NB];
    __shared__ int cur[NB];
    __shared__ int s[512];
    __shared__ int sdata[CH];

    int tid = threadIdx.x;
    int chunk0 = blockIdx.x * CH;

    for (int i = tid; i < NB; i += 512) scnt[i] = 0;
    __syncthreads();

#pragma unroll
    for (int k = 0; k < CH / 512; ++k) {
        int i = chunk0 + k * 512 + tid;
        if (i < e) atomicAdd(&scnt[dst[i] >> 8], 1);
    }
    __syncthreads();

    for (int b = tid; b < NB; b += 512)
        if (scnt[b]) sbase[b] = atomicAdd(&cursor[b], scnt[b]);

    s[tid] = (tid < NB) ? scnt[tid] : 0;
    __syncthreads();
    for (int off = 1; off < 512; off <<= 1) {
        int t = (tid >= off) ? s[tid - off] : 0;
        __syncthreads();
        s[tid] += t;
        __syncthreads();
    }
    if (tid < NB) {
        int ex = s[tid] - scnt[tid];
        lexcl[tid] = ex;
        cur[tid] = ex;
    }
    __syncthreads();

#pragma unroll
    for (int k = 0; k < CH / 512; ++k) {
        int i = chunk0 + k * 512 + tid;
        if (i < e) {
            int sv = src[i], d = dst[i];
            int b = d >> 8;
            int p = atomicAdd(&cur[b], 1);
            sdata[p] = (sv << 8) | (d & 255);
        }
    }
    __syncthreads();

    for (int b = tid; b < NB; b += 512) {
        int cb = scnt[b];
        if (cb) {
            int base = sbase[b];
            int start = lexcl[b];
            for (int k2 = 0; k2 < cb; ++k2)
                adj[base + k2] = sdata[start + k2];
        }
    }
}

// ---------------- per-bucket node-sort -> adj2 + rowptr + dinv (512 threads) ----------------
__global__ __launch_bounds__(512) void csr_kernel(
        const int* __restrict__ bhist, const int* __restrict__ boffs,
        const int* __restrict__ adj, int* __restrict__ adj2,
        int* __restrict__ rowptr, float* __restrict__ dinv, int n) {
    __shared__ int cnt[256];
    __shared__ int s[256];
    __shared__ int cur[256];
    int tid = threadIdx.x;
    int b = blockIdx.x;
    if (tid < 256) cnt[tid] = 0;
    __syncthreads();
    int ebeg = boffs[b], ecnt = bhist[b];
    for (int j = tid; j < ecnt; j += 512)
        atomicAdd(&cnt[adj[ebeg + j] & 255], 1);
    __syncthreads();
    int v = 0;
    if (tid < 256) { v = cnt[tid]; s[tid] = v; }
    __syncthreads();
    for (int off = 1; off < 256; off <<= 1) {
        int t = 0;
        if (tid < 256 && tid >= off) t = s[tid - off];
        __syncthreads();
        if (tid < 256) s[tid] += t;
        __syncthreads();
    }
    if (tid < 256) {
        int excl = s[tid] - v;
        cur[tid] = excl;
        int node = b * 256 + tid;
        if (node < n) {
            rowptr[node] = ebeg + excl;
            dinv[node] = rsqrtf((float)v + 1.0f);
        }
        if (node == n) rowptr[n] = ebeg + excl;   // sentinel == e
    }
    __syncthreads();
    for (int j = tid; j < ecnt; j += 512) {
        int w = adj[ebeg + j];
        int p = atomicAdd(&cur[w & 255], 1);
        adj2[ebeg + p] = w >> 8;
    }
}

// ---------------- layer 1 GEMM: split fp16 tables g1a (cols 0-15), g1b (cols 16-31) ----------------
__global__ __launch_bounds__(256) void gemm1_kernel(
        const float* __restrict__ x, const float* __restrict__ W1,
        const float* __restrict__ dinv, __half* __restrict__ g1a,
        __half* __restrict__ g1b, int n) {
    __shared__ float sW[64 * 32];     // sW[k*32+c] = W1[c*64+k]
    __shared__ float sX[32 * 65];     // padded stride 65
    int tid = threadIdx.x;
    for (int idx = tid; idx < 2048; idx += 256) {
        int k = idx >> 5, c = idx & 31;
        sW[idx] = W1[c * 64 + k];
    }
    int row0 = blockIdx.x * 32;
    for (int idx = tid; idx < 512; idx += 256) {   // 512 float4 = 32 rows x 16
        int r = idx >> 4, q = idx & 15;
        int grow = row0 + r;
        float4 v = (grow < n) ? ((const float4*)x)[(size_t)grow * 16 + q]
                              : make_float4(0.f, 0.f, 0.f, 0.f);
        float* dp = &sX[r * 65 + q * 4];
        dp[0] = v.x; dp[1] = v.y; dp[2] = v.z; dp[3] = v.w;
    }
    __syncthreads();
    int r = tid >> 3, cg = tid & 7;
    const float4* sW4 = (const float4*)sW;
    float4 acc = make_float4(0.f, 0.f, 0.f, 0.f);
#pragma unroll
    for (int k = 0; k < 64; ++k) {
        float xk = sX[r * 65 + k];
        float4 w = sW4[k * 8 + cg];
        acc.x += xk * w.x; acc.y += xk * w.y; acc.z += xk * w.z; acc.w += xk * w.w;
    }
    int grow = row0 + r;
    if (grow < n) {
        float di = dinv[grow];
        __half2 h0 = __float22half2_rn(make_float2(acc.x * di, acc.y * di));
        __half2 h1 = __float22half2_rn(make_float2(acc.z * di, acc.w * di));
        uint2 packed;
        packed.x = *(unsigned*)&h0;
        packed.y = *(unsigned*)&h1;
        if (cg < 4) ((uint2*)g1a)[(size_t)grow * 4 + cg] = packed;
        else        ((uint2*)g1b)[(size_t)grow * 4 + (cg - 4)] = packed;
    }
}

// ---------------- layer 1 aggregation: 8-wide unrolled CSR gather (plain loads) ----------------
__global__ __launch_bounds__(256) void agg1_kernel(
        const int* __restrict__ rowptr, const int* __restrict__ adj2,
        const float* __restrict__ dinv, const __half* __restrict__ gh,
        const float* __restrict__ b1, float* __restrict__ agg1, int n, int pass) {
    int t = blockIdx.x * blockDim.x + threadIdx.x;
    int node = t >> 3;
    if (node >= n) return;
    int c2 = t & 7;
    const unsigned* G = (const unsigned*)gh;
    float2 acc = u2f2(G[(size_t)node * 8 + c2]);   // self-loop (pre-scaled by dinv)
    int j = rowptr[node], end = rowptr[node + 1];
    for (; j + 7 < end; j += 8) {                   // 8 independent gathers in flight
        int s0 = adj2[j],     s1 = adj2[j + 1], s2 = adj2[j + 2], s3 = adj2[j + 3];
        int s4 = adj2[j + 4], s5 = adj2[j + 5], s6 = adj2[j + 6], s7 = adj2[j + 7];
        float2 v0 = u2f2(G[(size_t)s0 * 8 + c2]);
        float2 v1 = u2f2(G[(size_t)s1 * 8 + c2]);
        float2 v2 = u2f2(G[(size_t)s2 * 8 + c2]);
        float2 v3 = u2f2(G[(size_t)s3 * 8 + c2]);
        float2 v4 = u2f2(G[(size_t)s4 * 8 + c2]);
        float2 v5 = u2f2(G[(size_t)s5 * 8 + c2]);
        float2 v6 = u2f2(G[(size_t)s6 * 8 + c2]);
        float2 v7 = u2f2(G[(size_t)s7 * 8 + c2]);
        acc.x += ((v0.x + v1.x) + (v2.x + v3.x)) + ((v4.x + v5.x) + (v6.x + v7.x));
        acc.y += ((v0.y + v1.y) + (v2.y + v3.y)) + ((v4.y + v5.y) + (v6.y + v7.y));
    }
    for (; j + 3 < end; j += 4) {
        int s0 = adj2[j], s1 = adj2[j + 1], s2 = adj2[j + 2], s3 = adj2[j + 3];
        float2 v0 = u2f2(G[(size_t)s0 * 8 + c2]);
        float2 v1 = u2f2(G[(size_t)s1 * 8 + c2]);
        float2 v2 = u2f2(G[(size_t)s2 * 8 + c2]);
        float2 v3 = u2f2(G[(size_t)s3 * 8 + c2]);
        acc.x += (v0.x + v1.x) + (v2.x + v3.x);
        acc.y += (v0.y + v1.y) + (v2.y + v3.y);
    }
    for (; j < end; ++j) {
        float2 v = u2f2(G[(size_t)adj2[j] * 8 + c2]);
        acc.x += v.x; acc.y += v.y;
    }
    float di = dinv[node];
    float2 bb = ((const float2*)b1)[pass * 8 + c2];
    float2 outv = make_float2(bb.x + di * acc.x, bb.y + di * acc.y);
    ((float2*)agg1)[(size_t)node * 16 + pass * 8 + c2] = outv;
}

// ---------------- layer 2 GEMM: 64-row tile, float4 W reads ----------------
__global__ __launch_bounds__(256) void gemm2_kernel(
        const float* __restrict__ agg1, const float* __restrict__ W2,
        const float* __restrict__ dinv, __half* __restrict__ g2h, int n) {
    __shared__ float sW[32 * 16];     // sW[k*16+c] = W2[c*32+k]
    __shared__ float sH[64 * 33];     // padded
    int tid = threadIdx.x;
    for (int idx = tid; idx < 512; idx += 256) {
        int k = idx >> 4, c = idx & 15;
        sW[idx] = W2[c * 32 + k];
    }
    int row0 = blockIdx.x * 64;
    for (int idx = tid; idx < 512; idx += 256) {   // 512 float4 = 64 rows x 8
        int r = idx >> 3, q = idx & 7;
        int grow = row0 + r;
        float4 v = (grow < n) ? ((const float4*)agg1)[(size_t)grow * 8 + q]
                              : make_float4(0.f, 0.f, 0.f, 0.f);
        float* dp = &sH[r * 33 + q * 4];
        dp[0] = fmaxf(v.x, 0.f); dp[1] = fmaxf(v.y, 0.f);
        dp[2] = fmaxf(v.z, 0.f); dp[3] = fmaxf(v.w, 0.f);
    }
    __syncthreads();
    int r = tid >> 2, cg = tid & 3;
    const float4* sW4 = (const float4*)sW;
    float4 acc = make_float4(0.f, 0.f, 0.f, 0.f);
#pragma unroll
    for (int k = 0; k < 32; ++k) {
        float hk = sH[r * 33 + k];
        float4 w = sW4[k * 4 + cg];
        acc.x += hk * w.x; acc.y += hk * w.y; acc.z += hk * w.z; acc.w += hk * w.w;
    }
    int grow = row0 + r;
    if (grow < n) {
        float di = dinv[grow];
        __half2 h0 = __float22half2_rn(make_float2(acc.x * di, acc.y * di));
        __half2 h1 = __float22half2_rn(make_float2(acc.z * di, acc.w * di));
        uint2 packed;
        packed.x = *(unsigned*)&h0;
        packed.y = *(unsigned*)&h1;
        ((uint2*)g2h)[(size_t)grow * 4 + cg] = packed;
    }
}

// ---------------- layer 2 aggregation: 8-wide unrolled CSR gather (plain loads) ----------------
__global__ __launch_bounds__(256) void agg2_kernel(
        const int* __restrict__ rowptr, const int* __restrict__ adj2,
        const float* __restrict__ dinv, const __half* __restrict__ g2h,
        const float* __restrict__ b2, __half* __restrict__ zh, int n) {
    int t = blockIdx.x * blockDim.x + threadIdx.x;
    int node = t >> 3;
    if (node >= n) return;
    int c2 = t & 7;
    const unsigned* G = (const unsigned*)g2h;
    float2 acc = u2f2(G[(size_t)node * 8 + c2]);
    int j = rowptr[node], end = rowptr[node + 1];
    for (; j + 7 < end; j += 8) {
        int s0 = adj2[j],     s1 = adj2[j + 1], s2 = adj2[j + 2], s3 = adj2[j + 3];
        int s4 = adj2[j + 4], s5 = adj2[j + 5], s6 = adj2[j + 6], s7 = adj2[j + 7];
        float2 v0 = u2f2(G[(size_t)s0 * 8 + c2]);
        float2 v1 = u2f2(G[(size_t)s1 * 8 + c2]);
        float2 v2 = u2f2(G[(size_t)s2 * 8 + c2]);
        float2 v3 = u2f2(G[(size_t)s3 * 8 + c2]);
        float2 v4 = u2f2(G[(size_t)s4 * 8 + c2]);
        float2 v5 = u2f2(G[(size_t)s5 * 8 + c2]);
        float2 v6 = u2f2(G[(size_t)s6 * 8 + c2]);
        float2 v7 = u2f2(G[(size_t)s7 * 8 + c2]);
        acc.x += ((v0.x + v1.x) + (v2.x + v3.x)) + ((v4.x + v5.x) + (v6.x + v7.x));
        acc.y += ((v0.y + v1.y) + (v2.y + v3.y)) + ((v4.y + v5.y) + (v6.y + v7.y));
    }
    for (; j + 3 < end; j += 4) {
        int s0 = adj2[j], s1 = adj2[j + 1], s2 = adj2[j + 2], s3 = adj2[j + 3];
        float2 v0 = u2f2(G[(size_t)s0 * 8 + c2]);
        float2 v1 = u2f2(G[(size_t)s1 * 8 + c2]);
        float2 v2 = u2f2(G[(size_t)s2 * 8 + c2]);
        float2 v3 = u2f2(G[(size_t)s3 * 8 + c2]);
        acc.x += (v0.x + v1.x) + (v2.x + v3.x);
        acc.y += (v0.y + v1.y) + (v2.y + v3.y);
    }
    for (; j < end; ++j) {
        float2 v = u2f2(G[(size_t)adj2[j] * 8 + c2]);
        acc.x += v.x; acc.y += v.y;
    }
    float di = dinv[node];
    float2 bb = ((const float2*)b2)[c2];
    __half2 outv = __float22half2_rn(make_float2(bb.x + di * acc.x, bb.y + di * acc.y));
    ((__half2*)zh)[(size_t)node * 8 + c2] = outv;
}

// ---------------- decode: pair-lane, 2 edges per lane-pair (4 gathers in flight) ----------------
__global__ __launch_bounds__(256) void decode_kernel(
        const int* __restrict__ src, const int* __restrict__ dst,
        const __half* __restrict__ zh, float* __restrict__ out, int e) {
    int t = blockIdx.x * blockDim.x + threadIdx.x;
    int pair = t >> 1;                 // pair of consecutive edges
    int e0 = pair * 2;
    if (e0 >= e) return;
    int half = t & 1;
    u64 sv = *(const u64*)(src + e0);  // indices of both edges (e0 even -> 8B aligned)
    u64 dv = *(const u64*)(dst + e0);
    int s0 = (int)(unsigned)sv, s1 = (int)(sv >> 32);
    int d0 = (int)(unsigned)dv, d1 = (int)(dv >> 32);
    uint4 a0 = *((const uint4*)(zh + (size_t)s0 * 16) + half);
    uint4 b0 = *((const uint4*)(zh + (size_t)d0 * 16) + half);
    uint4 a1 = *((const uint4*)(zh + (size_t)s1 * 16) + half);
    uint4 b1 = *((const uint4*)(zh + (size_t)d1 * 16) + half);
    float p0 = 0.f, p1 = 0.f;
    p0 = dot2acc(a0.x, b0.x, p0); p0 = dot2acc(a0.y, b0.y, p0);
    p0 = dot2acc(a0.z, b0.z, p0); p0 = dot2acc(a0.w, b0.w, p0);
    p1 = dot2acc(a1.x, b1.x, p1); p1 = dot2acc(a1.y, b1.y, p1);
    p1 = dot2acc(a1.z, b1.z, p1); p1 = dot2acc(a1.w, b1.w, p1);
    float t0 = p0 + __shfl_xor(p0, 1, 64);
    float t1 = p1 + __shfl_xor(p1, 1, 64);
    if (half == 0) {
        float2 o;
        o.x = 1.0f / (1.0f + expf(-t0));
        o.y = 1.0f / (1.0f + expf(-t1));
        ((float2*)out)[pair] = o;
    }
}

extern "C" void kernel_launch(void* const* d_in, const int* in_sizes, int n_in,
                              void* d_out, int out_size, void* d_ws, size_t ws_size,
                              hipStream_t stream) {
    const float* x   = (const float*)d_in[0];
    const int* eidx  = (const int*)d_in[1];
    const float* W1  = (const float*)d_in[2];
    const float* b1  = (const float*)d_in[3];
    const float* W2  = (const float*)d_in[4];
    const float* b2  = (const float*)d_in[5];
    float* out = (float*)d_out;

    const int n = NN;
    const int e = NE;
    const int* src = eidx;
    const int* dst = eidx + e;

    // workspace layout (all segments 16B-aligned)
    int* bhist   = (int*)d_ws;                 // 512
    int* boffs   = bhist + 512;                // 512
    int* cursor  = boffs + 512;                // 512
    int* rowptr  = cursor + 512;               // NN+1 (pad 100004)
    int* adj     = rowptr + 100004;            // NE packed (dead after csr)
    int* adj2    = adj + e;                    // NE node-sorted srcs
    float* dinv  = (float*)(adj2 + e);         // NN
    __half* g1a  = (__half*)adj;               // alias: NN*16 halves (3.2MB) - cols 0..15
    __half* g1b  = g1a + (size_t)n * 16;       // NN*16 halves (3.2MB) - cols 16..31
    float* agg1  = dinv + n;                   // NN*32 f32
    __half* g2h  = (__half*)(agg1 + (size_t)n * 32);   // NN*16 halves
    __half* zh   = g2h + (size_t)n * 16;               // NN*16 halves
    int* part    = (int*)(zh + (size_t)n * 16);        // NBH*NB partial histograms

    dim3 blk(256);

    // CSR build (no memset anywhere: part rows are fully overwritten each call)
    bhist_kernel<<<NBH, blk, 0, stream>>>(dst, part, e);
    bscan_kernel<<<1, 512, 0, stream>>>(part, bhist, boffs, cursor);
    partition_kernel<<<NPART, 512, 0, stream>>>(src, dst, cursor, adj, e);
    csr_kernel<<<NB, 512, 0, stream>>>(bhist, boffs, adj, adj2, rowptr, dinv, n);

    // layer 1
    gemm1_kernel<<<(n + 31) / 32, blk, 0, stream>>>(x, W1, dinv, g1a, g1b, n);
    agg1_kernel<<<(n * 8 + 255) / 256, blk, 0, stream>>>(rowptr, adj2, dinv, g1a, b1, agg1, n, 0);
    agg1_kernel<<<(n * 8 + 255) / 256, blk, 0, stream>>>(rowptr, adj2, dinv, g1b, b1, agg1, n, 1);

    // layer 2
    gemm2_kernel<<<(n + 63) / 64, blk, 0, stream>>>(agg1, W2, dinv, g2h, n);
    agg2_kernel<<<(n * 8 + 255) / 256, blk, 0, stream>>>(rowptr, adj2, dinv, g2h, b2, zh, n);

    // decode: lane-pair handles 2 edges -> e threads total
    decode_kernel<<<(e + 255) / 256, blk, 0, stream>>>(src, dst, zh, out, e);
}